// Round 15
// baseline (246.889 us; speedup 1.0000x reference)
//
#include <hip/hip_runtime.h>

// DeltaModulationEncoder: x (16, 256, 8192) f32 -> spikes {-1,0,1} f32.
// Exact monolithic scan (recurrence serial per channel).
//
// Calibrated model: wall = 8192 x (hops x L) ; VGPR->VGPR dep L ~= 11 cyc at
// 1 wave/SIMD (R12: 5.5 hops=62 cyc/step, R13: 5 hops=55); SGPR/vcc-carried
// hops ~16 cyc (R14: 4 sgpr-hops=63 — regression, reverted). Memory is fully
// hidden by the hand-asm 16-deep pipeline (R12-R13 proven).
//
// This round: 4 all-VGPR hops — replace R13's {and(nth), fadd} tail with ONE
// v_bfi_b32 select among precomputed sums:
//   stubs: rp = fl(r+th), rm = fl(r-th)   (the reference's two possible
//                                          recon+net*th results, exact)
//   hop1:  err  = x - r
//   hop2:  m = th - |err| (Sterbenz-exact near boundary, strict at ==th),
//          smask = err>>31, sgnb = err & 0x80000000        (parallel)
//   hop3:  mask = m>>31, rpm = bfi(smask, rm, rp),
//          spcand = sgnb | 1.0f                            (parallel)
//   hop4:  r = bfi(mask, rpm, r), spike = mask & spcand    (parallel)
// Mask logic identical to R13 (passed, absmax 0.0); select of fl(r+-th) is
// bit-identical to adding the masked quantum; r is never -0.0f so the keep
// case is exact; spikes emerge directly as {+-1.0f, +0.0f}.
//
// Register map (fixed, compiler never touches):
//   v33 recon | v40 byte-voffset | v44 rp, v45 rm, v46 m/mask, v47 smask,
//   v48 err, v49 sgnb/spcand, v50 rpm
//   v[64+4j..67+4j]   q[j]  16-deep load pipeline (j=0..15)
//   v[128+4j..131+4j] spike set j (rotating: store-source regs overwritten
//                     only after vmcnt proves the store retired)
//   s8 = 0x3dcccccd (+0.1f), s10 = 0x80000000.
// Per slot: s_waitcnt vmcnt(30) [exact: my load and this spike-set's previous
// store are both 31 ops old], 4 steps, store(chunk), load(chunk+16).
// 256 blocks x 1 wave; lanes 0-15 each own one channel (4096 total).

constexpr int T    = 8192;
constexpr int NCH  = 4096;
constexpr int CPB  = 16;
constexpr int NBLK = NCH / CPB;   // 256

#define STEP(X,S) \
  "v_add_f32 v44, s8, v33\n\t"                  /* rp = th + r     (stub) */ \
  "v_subrev_f32 v45, s8, v33\n\t"               /* rm = r - th     (stub) */ \
  "v_sub_f32 v48, v" #X ", v33\n\t"             /* err = x - r      hop1 */ \
  "v_sub_f32_e64 v46, s8, |v48|\n\t"            /* m = th - |err|   hop2 */ \
  "v_ashrrev_i32 v47, 31, v48\n\t"              /* smask = err>>31  hop2 */ \
  "v_and_b32 v49, s10, v48\n\t"                 /* sgnb             hop2 */ \
  "v_ashrrev_i32 v46, 31, v46\n\t"              /* mask             hop3 */ \
  "v_bfi_b32 v50, v47, v45, v44\n\t"            /* rpm = sm?rm:rp   hop3 */ \
  "v_or_b32 v49, 0x3f800000, v49\n\t"           /* spcand = sgnb|1  hop3 */ \
  "v_bfi_b32 v33, v46, v50, v33\n\t"            /* r = mask?rpm:r   hop4 */ \
  "v_and_b32 v" #S ", v46, v49\n\t"             /* spike            hop4 */

#define SLOT_CLOB(Q0,Q1,Q2,Q3,P0,P1,P2,P3) \
  "memory","v33","v44","v45","v46","v47","v48","v49","v50", \
  "v" #Q0,"v" #Q1,"v" #Q2,"v" #Q3,"v" #P0,"v" #P1,"v" #P2,"v" #P3

// Steady-state slot: wait(exact) + 4 steps + store(chunk) + load(chunk+16).
#define SLOT(Q0,Q1,Q2,Q3,P0,P1,P2,P3,OFFS,OFFL) asm volatile( \
  "s_waitcnt vmcnt(30)\n\t" \
  STEP(Q0,P0) STEP(Q1,P1) STEP(Q2,P2) STEP(Q3,P3) \
  "global_store_dwordx4 v40, v[" #P0 ":" #P3 "], %1 offset:" #OFFS "\n\t" \
  "global_load_dwordx4 v[" #Q0 ":" #Q3 "], v40, %0 offset:" #OFFL "\n\t" \
  :: "s"(xp), "s"(op) : SLOT_CLOB(Q0,Q1,Q2,Q3,P0,P1,P2,P3))

// Final-iteration slot: everything drained beforehand; no wait, no load.
#define SLOTND(Q0,Q1,Q2,Q3,P0,P1,P2,P3,OFFS) asm volatile( \
  STEP(Q0,P0) STEP(Q1,P1) STEP(Q2,P2) STEP(Q3,P3) \
  "global_store_dwordx4 v40, v[" #P0 ":" #P3 "], %1 offset:" #OFFS "\n\t" \
  :: "s"(xp), "s"(op) : SLOT_CLOB(Q0,Q1,Q2,Q3,P0,P1,P2,P3))

__global__ __launch_bounds__(64, 1) void dm_scan(const float* __restrict__ x,
                                                 float* __restrict__ out) {
    const int lane = threadIdx.x;
    if (lane >= CPB) return;                  // exec = 0xFFFF for the rest
    const int ch = blockIdx.x * CPB + lane;

    const float* xp = x;                      // uniform -> "s" (SADDR base)
    float*       op = out;
    unsigned off0 = (unsigned)ch * (unsigned)(T * 4);   // per-lane byte offset

    // Prologue: consts, recon=0, voffset, fill the 16-slot pipeline, drain.
    asm volatile(
        "s_mov_b32 s8, 0x3dcccccd\n\t"        // +0.1f
        "s_mov_b32 s10, 0x80000000\n\t"       // sign mask
        "v_mov_b32 v33, 0\n\t"
        "v_mov_b32 v40, %2\n\t"
        "global_load_dwordx4 v[64:67],   v40, %0\n\t"
        "global_load_dwordx4 v[68:71],   v40, %0 offset:16\n\t"
        "global_load_dwordx4 v[72:75],   v40, %0 offset:32\n\t"
        "global_load_dwordx4 v[76:79],   v40, %0 offset:48\n\t"
        "global_load_dwordx4 v[80:83],   v40, %0 offset:64\n\t"
        "global_load_dwordx4 v[84:87],   v40, %0 offset:80\n\t"
        "global_load_dwordx4 v[88:91],   v40, %0 offset:96\n\t"
        "global_load_dwordx4 v[92:95],   v40, %0 offset:112\n\t"
        "global_load_dwordx4 v[96:99],   v40, %0 offset:128\n\t"
        "global_load_dwordx4 v[100:103], v40, %0 offset:144\n\t"
        "global_load_dwordx4 v[104:107], v40, %0 offset:160\n\t"
        "global_load_dwordx4 v[108:111], v40, %0 offset:176\n\t"
        "global_load_dwordx4 v[112:115], v40, %0 offset:192\n\t"
        "global_load_dwordx4 v[116:119], v40, %0 offset:208\n\t"
        "global_load_dwordx4 v[120:123], v40, %0 offset:224\n\t"
        "global_load_dwordx4 v[124:127], v40, %0 offset:240\n\t"
        "s_waitcnt vmcnt(0)\n\t"
        :: "s"(xp), "s"(op), "v"(off0)
        : "memory","s8","s10",
          "v33","v40","v44","v45","v46","v47","v48","v49","v50",
          "v64","v65","v66","v67","v68","v69","v70","v71",
          "v72","v73","v74","v75","v76","v77","v78","v79",
          "v80","v81","v82","v83","v84","v85","v86","v87",
          "v88","v89","v90","v91","v92","v93","v94","v95",
          "v96","v97","v98","v99","v100","v101","v102","v103",
          "v104","v105","v106","v107","v108","v109","v110","v111",
          "v112","v113","v114","v115","v116","v117","v118","v119",
          "v120","v121","v122","v123","v124","v125","v126","v127");

    // 127 iterations x 16 chunks; slot j consumes chunk (16*it + j) and
    // prefetches chunk (16*it + j + 16). Last prefetch: it=126, j=15 ->
    // chunk 2047 (in bounds).
#pragma clang loop unroll(disable)
    for (int it = 0; it < 127; ++it) {
        SLOT( 64, 65, 66, 67, 128,129,130,131,   0, 256);
        SLOT( 68, 69, 70, 71, 132,133,134,135,  16, 272);
        SLOT( 72, 73, 74, 75, 136,137,138,139,  32, 288);
        SLOT( 76, 77, 78, 79, 140,141,142,143,  48, 304);
        SLOT( 80, 81, 82, 83, 144,145,146,147,  64, 320);
        SLOT( 84, 85, 86, 87, 148,149,150,151,  80, 336);
        SLOT( 88, 89, 90, 91, 152,153,154,155,  96, 352);
        SLOT( 92, 93, 94, 95, 156,157,158,159, 112, 368);
        SLOT( 96, 97, 98, 99, 160,161,162,163, 128, 384);
        SLOT(100,101,102,103, 164,165,166,167, 144, 400);
        SLOT(104,105,106,107, 168,169,170,171, 160, 416);
        SLOT(108,109,110,111, 172,173,174,175, 176, 432);
        SLOT(112,113,114,115, 176,177,178,179, 192, 448);
        SLOT(116,117,118,119, 180,181,182,183, 208, 464);
        SLOT(120,121,122,123, 184,185,186,187, 224, 480);
        SLOT(124,125,126,127, 188,189,190,191, 240, 496);
        asm volatile("v_add_u32 v40, 0x100, v40" ::: "v40");
    }

    // Final 16 chunks (2032..2047): drain once, then compute+store only.
    asm volatile("s_waitcnt vmcnt(0)" ::: "memory");
    SLOTND( 64, 65, 66, 67, 128,129,130,131,   0);
    SLOTND( 68, 69, 70, 71, 132,133,134,135,  16);
    SLOTND( 72, 73, 74, 75, 136,137,138,139,  32);
    SLOTND( 76, 77, 78, 79, 140,141,142,143,  48);
    SLOTND( 80, 81, 82, 83, 144,145,146,147,  64);
    SLOTND( 84, 85, 86, 87, 148,149,150,151,  80);
    SLOTND( 88, 89, 90, 91, 152,153,154,155,  96);
    SLOTND( 92, 93, 94, 95, 156,157,158,159, 112);
    SLOTND( 96, 97, 98, 99, 160,161,162,163, 128);
    SLOTND(100,101,102,103, 164,165,166,167, 144);
    SLOTND(104,105,106,107, 168,169,170,171, 160);
    SLOTND(108,109,110,111, 172,173,174,175, 176);
    SLOTND(112,113,114,115, 176,177,178,179, 192);
    SLOTND(116,117,118,119, 180,181,182,183, 208);
    SLOTND(120,121,122,123, 184,185,186,187, 224);
    SLOTND(124,125,126,127, 188,189,190,191, 240);
}

extern "C" void kernel_launch(void* const* d_in, const int* in_sizes, int n_in,
                              void* d_out, int out_size, void* d_ws, size_t ws_size,
                              hipStream_t stream) {
    const float* x   = (const float*)d_in[0];
    float*       out = (float*)d_out;
    dm_scan<<<NBLK, 64, 0, stream>>>(x, out);
}